// Round 6
// baseline (1117.438 us; speedup 1.0000x reference)
//
#include <hip/hip_runtime.h>
#include <hip/hip_cooperative_groups.h>

namespace cg = cooperative_groups;

// x (16,256,128,128) fp32; W1 (128,256); b1 (128); W2 (256,128); b2 (256).
// out = selected (16,128,...) ++ remaining (16,128,...): channel permutation.
#define NB 16
#define C  256
#define CH 128
#define HW 16384              // 128*128 floats per plane
#define PLANES (NB * C)       // 4096
#define NCHUNK 4              // images per chunk
#define CPLANES (NCHUNK * C)  // 1024 planes per chunk (67 MB)
#define GRID 1024             // cooperative grid: 4 blocks/CU, co-resident

typedef float vfloat4 __attribute__((ext_vector_type(4)));

// ================= fused cooperative pipeline =============================
// Software-pipelined chunks: gather(c) runs 2 grid-sync steps after mean(c),
// so its source planes sit at <=134 MB reuse distance in the 256 MB L3
// (round-3 measurement: full-buffer reuse distance got only ~50% hits).
// NT loads (gather src, last use) + NT stores (output) keep the streams
// from evicting the live window.
__global__ __launch_bounds__(256) void fused_kernel(
        const float* __restrict__ x,
        const float* __restrict__ W1, const float* __restrict__ b1,
        const float* __restrict__ W2, const float* __restrict__ b2,
        float* __restrict__ out, float* __restrict__ z, int* __restrict__ perm)
{
    cg::grid_group grid = cg::this_grid();
    const int t = threadIdx.x;

    __shared__ float zs[C];
    __shared__ float hs[CH];
    __shared__ float sc[C];
    __shared__ float wsum[4];

    auto mean_plane = [&](int plane) {
        const vfloat4* xp = (const vfloat4*)(x + (size_t)plane * HW);
        float s = 0.0f;
#pragma unroll
        for (int i = 0; i < 16; ++i) {
            vfloat4 v = xp[t + i * 256];
            s += (v.x + v.y) + (v.z + v.w);
        }
#pragma unroll
        for (int off = 32; off > 0; off >>= 1) s += __shfl_down(s, off, 64);
        const int lane = t & 63, wave = t >> 6;
        if (lane == 0) wsum[wave] = s;
        __syncthreads();
        if (t == 0)
            z[plane] = ((wsum[0] + wsum[1]) + (wsum[2] + wsum[3]))
                       * (1.0f / (float)HW);
        __syncthreads();                       // wsum reusable next task
    };

    auto mlp_img = [&](int n) {
        zs[t] = z[n * C + t];
        __syncthreads();
        if (t < CH) {
            float acc = b1[t];
            const float* w = W1 + t * C;
            for (int k = 0; k < C; ++k) acc = fmaf(zs[k], w[k], acc);
            hs[t] = fmaxf(acc, 0.0f);
        }
        __syncthreads();
        {
            float acc = b2[t];
            const float* w = W2 + t * CH;
            for (int k = 0; k < CH; ++k) acc = fmaf(hs[k], w[k], acc);
            sc[t] = acc;                       // logit; order == sigmoid order
        }
        __syncthreads();
        const float mysc = sc[t];
        int rank = 0;
        for (int j = 0; j < C; ++j) {
            float o = sc[j];
            // descending, stable: j precedes t if o > mysc, or tie & j < t
            rank += (o > mysc) || (o == mysc && j < t);
        }
        perm[n * C + rank] = t;
        __syncthreads();                       // shared arrays reusable
    };

    auto gather_plane = [&](int j, int c) {
        const int n = c * NCHUNK + (j >> 8);
        const int p = j & 255;
        const int src = perm[n * C + p];
        const vfloat4* sp = (const vfloat4*)(x + ((size_t)n * C + src) * HW);
        const size_t dstPlane = (p < CH)
            ? ((size_t)n * CH + p)
            : ((size_t)NB * CH + (size_t)n * CH + (p - CH));
        vfloat4* dp = (vfloat4*)(out + dstPlane * HW);
#pragma unroll
        for (int i = 0; i < 16; ++i) {
            vfloat4 v = __builtin_nontemporal_load(sp + t + i * 256);
            __builtin_nontemporal_store(v, dp + t + i * 256);
        }
    };

    // One pipeline step: optional gather chunk gC, mean chunk mC, mlp chunk pC.
    auto run_step = [&](int gC, int mC, int pC) {
        int T = 0;
        if (gC >= 0) T += CPLANES;
        const int gEnd = T;
        if (mC >= 0) T += CPLANES;
        const int mEnd = T;
        if (pC >= 0) T += NCHUNK;
        for (int i = blockIdx.x; i < T; i += GRID) {
            if (i < gEnd)      gather_plane(i, gC);
            else if (i < mEnd) mean_plane(mC * CPLANES + (i - gEnd));
            else               mlp_img(pC * NCHUNK + (i - mEnd));
        }
        grid.sync();
    };

    run_step(-1,  0, -1);
    run_step(-1,  1,  0);
    run_step( 0,  2,  1);
    run_step( 1,  3,  2);
    run_step( 2, -1,  3);
    // final step needs no trailing sync
    for (int i = blockIdx.x; i < CPLANES; i += GRID) gather_plane(i, 3);
}

// ================= fallback: round-4 three-kernel path ====================
__global__ __launch_bounds__(256) void mean_kernel(const float* __restrict__ x,
                                                   float* __restrict__ z) {
    const int plane = blockIdx.x;
    const vfloat4* xp = (const vfloat4*)(x + (size_t)plane * HW);
    const int t = threadIdx.x;
    float s = 0.0f;
#pragma unroll
    for (int i = 0; i < 16; ++i) {
        vfloat4 v = xp[t + i * 256];
        s += (v.x + v.y) + (v.z + v.w);
    }
#pragma unroll
    for (int off = 32; off > 0; off >>= 1) s += __shfl_down(s, off, 64);
    __shared__ float wsum[4];
    const int lane = t & 63, wave = t >> 6;
    if (lane == 0) wsum[wave] = s;
    __syncthreads();
    if (t == 0)
        z[plane] = ((wsum[0] + wsum[1]) + (wsum[2] + wsum[3]))
                   * (1.0f / (float)HW);
}

__global__ __launch_bounds__(256) void mlp_sort_kernel(
        const float* __restrict__ z,
        const float* __restrict__ W1, const float* __restrict__ b1,
        const float* __restrict__ W2, const float* __restrict__ b2,
        int* __restrict__ perm) {
    const int n = blockIdx.x;
    const int t = threadIdx.x;
    __shared__ float zs[C];
    __shared__ float hs[CH];
    __shared__ float sc[C];
    zs[t] = z[n * C + t];
    __syncthreads();
    if (t < CH) {
        float acc = b1[t];
        const float* w = W1 + t * C;
        for (int k = 0; k < C; ++k) acc = fmaf(zs[k], w[k], acc);
        hs[t] = fmaxf(acc, 0.0f);
    }
    __syncthreads();
    {
        float acc = b2[t];
        const float* w = W2 + t * CH;
        for (int k = 0; k < CH; ++k) acc = fmaf(hs[k], w[k], acc);
        sc[t] = acc;
    }
    __syncthreads();
    const float mysc = sc[t];
    int rank = 0;
    for (int j = 0; j < C; ++j) {
        float o = sc[j];
        rank += (o > mysc) || (o == mysc && j < t);
    }
    perm[n * C + rank] = t;
}

__global__ __launch_bounds__(256) void gather_kernel(const float* __restrict__ x,
                                                     const int* __restrict__ perm,
                                                     float* __restrict__ out) {
    const int bid = blockIdx.x;                  // 0..8191
    const int b = (PLANES - 1) - (bid >> 1);     // output plane 4095..0
    const int half = bid & 1;
    const int n = b >> 8;
    const int p = b & 255;
    const int src = perm[b];
    const vfloat4* sp = (const vfloat4*)(x + ((size_t)n * C + src) * HW
                                           + (size_t)half * (HW / 2));
    const size_t dstPlane = (p < CH)
        ? ((size_t)n * CH + p)
        : ((size_t)NB * CH + (size_t)n * CH + (p - CH));
    vfloat4* dp = (vfloat4*)(out + dstPlane * HW + (size_t)half * (HW / 2));
    const int t = threadIdx.x;
#pragma unroll
    for (int i = 0; i < 8; ++i) {
        vfloat4 v = sp[t + i * 256];
        __builtin_nontemporal_store(v, dp + t + i * 256);
    }
}

extern "C" void kernel_launch(void* const* d_in, const int* in_sizes, int n_in,
                              void* d_out, int out_size, void* d_ws, size_t ws_size,
                              hipStream_t stream) {
    const float* x  = (const float*)d_in[0];
    const float* W1 = (const float*)d_in[1];
    const float* b1 = (const float*)d_in[2];
    const float* W2 = (const float*)d_in[3];
    const float* b2 = (const float*)d_in[4];
    float* out = (float*)d_out;

    float* z   = (float*)d_ws;                                 // 4096 floats
    int*  perm = (int*)((char*)d_ws + PLANES * sizeof(float)); // 4096 ints

    static int coop = -1;
    if (coop < 0) {
        int dev = 0;
        hipGetDevice(&dev);
        int v = 0;
        hipDeviceGetAttribute(&v, hipDeviceAttributeCooperativeLaunch, dev);
        coop = v;
    }

    bool launched = false;
    if (coop) {
        void* args[] = {(void*)&x, (void*)&W1, (void*)&b1, (void*)&W2,
                        (void*)&b2, (void*)&out, (void*)&z, (void*)&perm};
        hipError_t err = hipLaunchCooperativeKernel((void*)fused_kernel,
                                                    dim3(GRID), dim3(256),
                                                    args, 0, stream);
        launched = (err == hipSuccess);
    }
    if (!launched) {
        // round-4 fallback path (last measured 498 us end-to-end)
        mean_kernel<<<PLANES, 256, 0, stream>>>(x, z);
        mlp_sort_kernel<<<NB, 256, 0, stream>>>(z, W1, b1, W2, b2, perm);
        gather_kernel<<<PLANES * 2, 256, 0, stream>>>(x, perm, out);
    }
}